// Round 1
// baseline (126.427 us; speedup 1.0000x reference)
//
#include <hip/hip_runtime.h>

// Problem constants
#define EDIM 1024
#define NROW 32

constexpr int AUD_ELEMS  = 32 * 1024;          // 32768  (audio_output 32x1024)
constexpr int CONN_ELEMS = 1024 * 4096;        // 4194304 (connections copy)
constexpr int INW_ELEMS  = 3 * 1024 * 1024;    // 3145728 (in_proj_w copy)
constexpr int OUTW_ELEMS = 1024 * 1024;        // 1048576 (out_proj_w copy)

constexpr int AUD_F4   = AUD_ELEMS / 4;        // 8192
constexpr int CONN_F4  = CONN_ELEMS / 4;       // 1048576
constexpr int INW_F4   = INW_ELEMS / 4;        // 786432
constexpr int OUTW_F4  = OUTW_ELEMS / 4;       // 262144
constexpr int TOTAL_F4 = AUD_F4 + CONN_F4 + INW_F4 + OUTW_F4;  // 2105344

// ---------------------------------------------------------------------------
// Fused output copy: zero the audio region (atomics accumulate into it later),
// then copy connections / in_proj_w / out_proj_w verbatim (STDP delta == 0
// exactly because TAU_POS == TAU_NEG).
// ---------------------------------------------------------------------------
__global__ __launch_bounds__(256) void copy_zero_kernel(
    const float4* __restrict__ conn, const float4* __restrict__ inw,
    const float4* __restrict__ outw, float4* __restrict__ out)
{
    int i = blockIdx.x * 256 + threadIdx.x;
    if (i >= TOTAL_F4) return;
    float4 v;
    if (i < AUD_F4) {
        v = make_float4(0.f, 0.f, 0.f, 0.f);
    } else if (i < AUD_F4 + CONN_F4) {
        v = conn[i - AUD_F4];
    } else if (i < AUD_F4 + CONN_F4 + INW_F4) {
        v = inw[i - (AUD_F4 + CONN_F4)];
    } else {
        v = outw[i - (AUD_F4 + CONN_F4 + INW_F4)];
    }
    out[i] = v;
}

// ---------------------------------------------------------------------------
// C[32 x 1024] = A[32 x 1024] @ B[1024 x 1024]^T + bias
// (row-dot form: C[n,e] = dot(A[n,:], B[e,:]) + bias[e])
// One wave per (e, n-group-of-8). Block = 4 waves sharing one n-group and
// 4 consecutive e's -> 8 A rows reused via L1, B rows streamed coalesced.
// Grid: 1024 blocks x 256 threads = 4096 waves.
// ---------------------------------------------------------------------------
__global__ __launch_bounds__(256) void gemm_bt32_kernel(
    const float* __restrict__ A, const float* __restrict__ B,
    const float* __restrict__ bias, float* __restrict__ C)
{
    int gw   = (blockIdx.x * 256 + threadIdx.x) >> 6;  // global wave id [0,4096)
    int lane = threadIdx.x & 63;
    int e    = gw & 1023;
    int n0   = (gw >> 10) * 8;

    const float4* Br = (const float4*)(B + (size_t)e * EDIM);
    float4 b0 = Br[lane], b1 = Br[lane + 64], b2 = Br[lane + 128], b3 = Br[lane + 192];
    float be = bias[e];

#pragma unroll
    for (int i = 0; i < 8; ++i) {
        int n = n0 + i;
        const float4* Ar = (const float4*)(A + (size_t)n * EDIM);
        float4 a0 = Ar[lane], a1 = Ar[lane + 64], a2 = Ar[lane + 128], a3 = Ar[lane + 192];
        float s = a0.x*b0.x + a0.y*b0.y + a0.z*b0.z + a0.w*b0.w;
        s += a1.x*b1.x + a1.y*b1.y + a1.z*b1.z + a1.w*b1.w;
        s += a2.x*b2.x + a2.y*b2.y + a2.z*b2.z + a2.w*b2.w;
        s += a3.x*b3.x + a3.y*b3.y + a3.z*b3.z + a3.w*b3.w;
#pragma unroll
        for (int off = 32; off > 0; off >>= 1) s += __shfl_down(s, off);
        if (lane == 0) C[(size_t)n * EDIM + e] = s + be;
    }
}

// ---------------------------------------------------------------------------
// audio[32 x 1024] += attn[32 x 1024] @ connections[:, :1024]
// connections is row-major (1024 x 4096); row k's first 1024 cols are one
// contiguous 4 KB chunk -> coalesced float4 loads across 256 threads.
// Grid: 128 blocks = (16 k-chunks of 64) x (8 n-groups of 4). Each thread
// owns one j-quad and 4 n accumulators; partial results land via atomicAdd
// into the pre-zeroed audio region (16-way contention, f32 device-scope).
// ---------------------------------------------------------------------------
__global__ __launch_bounds__(256) void audio_kernel(
    const float* __restrict__ attn, const float* __restrict__ conn,
    float* __restrict__ out)
{
    int g  = blockIdx.x & 7;       // n-group
    int kc = blockIdx.x >> 3;      // k-chunk
    int n0 = g * 4;
    int k0 = kc * 64;
    int t  = threadIdx.x;          // j-quad index: j = 4t .. 4t+3

    __shared__ float sa[256];      // attn[n0..n0+3][k0..k0+63]
    sa[t] = attn[(size_t)(n0 + (t >> 6)) * EDIM + k0 + (t & 63)];
    __syncthreads();

    const float4* c4 = (const float4*)conn;   // 1024 float4 per row (4096 cols)
    float4 acc0 = {0,0,0,0}, acc1 = {0,0,0,0}, acc2 = {0,0,0,0}, acc3 = {0,0,0,0};
#pragma unroll 4
    for (int k = 0; k < 64; ++k) {
        float4 c = c4[(size_t)(k0 + k) * 1024 + t];
        float a0v = sa[k], a1v = sa[64 + k], a2v = sa[128 + k], a3v = sa[192 + k];
        acc0.x += a0v*c.x; acc0.y += a0v*c.y; acc0.z += a0v*c.z; acc0.w += a0v*c.w;
        acc1.x += a1v*c.x; acc1.y += a1v*c.y; acc1.z += a1v*c.z; acc1.w += a1v*c.w;
        acc2.x += a2v*c.x; acc2.y += a2v*c.y; acc2.z += a2v*c.z; acc2.w += a2v*c.w;
        acc3.x += a3v*c.x; acc3.y += a3v*c.y; acc3.z += a3v*c.z; acc3.w += a3v*c.w;
    }

    float* o0 = out + (size_t)(n0 + 0) * 1024 + 4 * t;
    float* o1 = out + (size_t)(n0 + 1) * 1024 + 4 * t;
    float* o2 = out + (size_t)(n0 + 2) * 1024 + 4 * t;
    float* o3 = out + (size_t)(n0 + 3) * 1024 + 4 * t;
    atomicAdd(o0 + 0, acc0.x); atomicAdd(o0 + 1, acc0.y); atomicAdd(o0 + 2, acc0.z); atomicAdd(o0 + 3, acc0.w);
    atomicAdd(o1 + 0, acc1.x); atomicAdd(o1 + 1, acc1.y); atomicAdd(o1 + 2, acc1.z); atomicAdd(o1 + 3, acc1.w);
    atomicAdd(o2 + 0, acc2.x); atomicAdd(o2 + 1, acc2.y); atomicAdd(o2 + 2, acc2.z); atomicAdd(o2 + 3, acc2.w);
    atomicAdd(o3 + 0, acc3.x); atomicAdd(o3 + 1, acc3.y); atomicAdd(o3 + 2, acc3.z); atomicAdd(o3 + 3, acc3.w);
}

extern "C" void kernel_launch(void* const* d_in, const int* in_sizes, int n_in,
                              void* d_out, int out_size, void* d_ws, size_t ws_size,
                              hipStream_t stream) {
    // setup_inputs order:
    // 0 av_value, 1 av_key, 2 av_query, 3 in_proj_w, 4 in_proj_b,
    // 5 out_proj_w, 6 out_proj_b, 7 connections
    const float* av_value   = (const float*)d_in[0];
    const float* in_proj_w  = (const float*)d_in[3];
    const float* in_proj_b  = (const float*)d_in[4];
    const float* out_proj_w = (const float*)d_in[5];
    const float* out_proj_b = (const float*)d_in[6];
    const float* conn       = (const float*)d_in[7];
    float* out = (float*)d_out;

    float* vp   = (float*)d_ws;            // 32x1024
    float* attn = vp + AUD_ELEMS;          // 32x1024

    // 1) zero audio region + verbatim weight copies (zero STDP delta)
    copy_zero_kernel<<<(TOTAL_F4 + 255) / 256, 256, 0, stream>>>(
        (const float4*)conn, (const float4*)in_proj_w,
        (const float4*)out_proj_w, (float4*)out);

    // 2) vp = av_value @ Wv^T + bv   (Wv = in_proj_w rows [2048,3072))
    gemm_bt32_kernel<<<1024, 256, 0, stream>>>(
        av_value, in_proj_w + 2 * EDIM * EDIM, in_proj_b + 2 * EDIM, vp);

    // 3) attn_out = vp @ Wo^T + bo   (softmax over size-1 axis == identity)
    gemm_bt32_kernel<<<1024, 256, 0, stream>>>(
        vp, out_proj_w, out_proj_b, attn);

    // 4) audio = attn_out @ connections[:, :1024]
    audio_kernel<<<128, 256, 0, stream>>>(attn, conn, out);
}